// Round 15
// baseline (460.000 us; speedup 1.0000x reference)
//
#include <hip/hip_runtime.h>
#include <cstdint>
#include <cstddef>

// Shapes (fixed): B=64, N=4, P=128, d=h=256, totP=512, feat=131072
#define P_    128
#define H_    256
#define FEAT_ 131072

// ---------------------------------------------------------------------------
// FUSED independent-stage kernel: blocks 0..255 run the sim+deg+normalize
// body (-> An); blocks 256..767 run layer-1 gemm (x@W1+b1 -> XW1).
// Sim body retiled to the conflict-free 4-split fragment layout (pad 132):
// a-frags tp*4 / 64+tp*4 (broadcast), b-frags tq*4 / 64+tq*4 (2-way, free).
// Gemm body verbatim R11/R14.
// ---------------------------------------------------------------------------
#define SIM_XS   0      // [16][132] = 2112
#define SIM_RED  2112   // [128][17] = 2176
#define SIM_DIAG 4288   // 128
#define SIM_INV  4416   // 128
#define SIM_DINV 4544   // 128  (total 4672)
#define GE_AS    0      // [16][132] = 2112
#define GE_WS    2112   // [16][132] = 2112 (total 4224)

__global__ __launch_bounds__(256) void k_simgemm(
    const float* __restrict__ x, const float* __restrict__ mask,
    float* __restrict__ An,
    const float* __restrict__ W, const float* __restrict__ bias,
    float* __restrict__ out) {
  __shared__ float smem[4672];
  const int bid = blockIdx.x;
  const int t = threadIdx.x, tp = t >> 4, tq = t & 15;

  if (bid < 256) {
    // ------------- sim + deg + sym-normalize (4-split retile) -------------
    const int blk = bid;
    const float* Xb = x + (size_t)blk * (128 * 256);

    float v[8][8];
    #pragma unroll
    for (int i = 0; i < 8; ++i)
      #pragma unroll
      for (int j = 0; j < 8; ++j) v[i][j] = 0.f;

    for (int kc = 0; kc < 16; ++kc) {
      __syncthreads();
      #pragma unroll
      for (int l = 0; l < 2; ++l) {
        const int f = t + 256 * l;
        const int row = f >> 2, k4 = (f & 3) * 4;
        const float4 x4 = *(const float4*)(Xb + (size_t)row * 256 + kc * 16 + k4);
        smem[SIM_XS + (k4 + 0) * 132 + row] = x4.x;
        smem[SIM_XS + (k4 + 1) * 132 + row] = x4.y;
        smem[SIM_XS + (k4 + 2) * 132 + row] = x4.z;
        smem[SIM_XS + (k4 + 3) * 132 + row] = x4.w;
      }
      __syncthreads();
      #pragma unroll
      for (int k = 0; k < 16; ++k) {
        const float4 a0 = *(const float4*)&smem[SIM_XS + k * 132 + tp * 4];
        const float4 a1 = *(const float4*)&smem[SIM_XS + k * 132 + 64 + tp * 4];
        const float4 b0 = *(const float4*)&smem[SIM_XS + k * 132 + tq * 4];
        const float4 b1 = *(const float4*)&smem[SIM_XS + k * 132 + 64 + tq * 4];
        const float a[8] = {a0.x, a0.y, a0.z, a0.w, a1.x, a1.y, a1.z, a1.w};
        const float b[8] = {b0.x, b0.y, b0.z, b0.w, b1.x, b1.y, b1.z, b1.w};
        #pragma unroll
        for (int i = 0; i < 8; ++i)
          #pragma unroll
          for (int j = 0; j < 8; ++j) v[i][j] += a[i] * b[j];
      }
    }

    // row/col maps: ri(i) = i<4 ? tp*4+i : 64+tp*4+(i-4); cj(j) analogous.
    // diagonal (only threads tp==tq hold ri==cj cells)
    if (tp == tq) {
      #pragma unroll
      for (int i = 0; i < 8; ++i) {
        const int r = (i < 4) ? (tp * 4 + i) : (64 + tp * 4 + (i - 4));
        smem[SIM_DIAG + r] = v[i][i];
      }
    }
    __syncthreads();
    if (t < 128)
      smem[SIM_INV + t] = 1.0f / fmaxf(sqrtf(smem[SIM_DIAG + t]), 1e-12f);
    __syncthreads();

    float ivq[8];
    #pragma unroll
    for (int j = 0; j < 8; ++j) {
      const int c = (j < 4) ? (tq * 4 + j) : (64 + tq * 4 + (j - 4));
      ivq[j] = smem[SIM_INV + c];
    }

    #pragma unroll
    for (int i = 0; i < 8; ++i) {
      const int r = (i < 4) ? (tp * 4 + i) : (64 + tp * 4 + (i - 4));
      const float ivp = smem[SIM_INV + r];
      const float4 m0 = *(const float4*)(mask + r * 128 + tq * 4);
      const float4 m1 = *(const float4*)(mask + r * 128 + 64 + tq * 4);
      const float mm[8] = {m0.x, m0.y, m0.z, m0.w, m1.x, m1.y, m1.z, m1.w};
      float s = 0.f;
      #pragma unroll
      for (int j = 0; j < 8; ++j) {
        const int c = (j < 4) ? (tq * 4 + j) : (64 + tq * 4 + (j - 4));
        const float vv = (r == c) ? 0.0f
                                  : (v[i][j] * ivp * ivq[j] + 1.0f) * 0.5f * mm[j];
        v[i][j] = vv;
        s += vv;
      }
      smem[SIM_RED + r * 17 + tq] = s;
    }
    __syncthreads();
    if (t < 128) {
      float sm = 0.f;
      #pragma unroll
      for (int u = 0; u < 16; ++u) sm += smem[SIM_RED + t * 17 + u];
      const float deg = 1.0f + sm;
      smem[SIM_DINV + t] = (deg > 0.0f) ? rsqrtf(fmaxf(deg, 1e-12f)) : 0.0f;
    }
    __syncthreads();

    float dq[8];
    #pragma unroll
    for (int j = 0; j < 8; ++j) {
      const int c = (j < 4) ? (tq * 4 + j) : (64 + tq * 4 + (j - 4));
      dq[j] = smem[SIM_DINV + c];
    }
    float* Ab = An + (size_t)blk * 16384;
    #pragma unroll
    for (int i = 0; i < 8; ++i) {
      const int r = (i < 4) ? (tp * 4 + i) : (64 + tp * 4 + (i - 4));
      const float dp = smem[SIM_DINV + r];
      float o[8];
      #pragma unroll
      for (int j = 0; j < 8; ++j) {
        const int c = (j < 4) ? (tq * 4 + j) : (64 + tq * 4 + (j - 4));
        o[j] = (r == c) ? dp * dq[j] : v[i][j] * dp * dq[j];
      }
      *(float4*)(Ab + (size_t)r * 128 + tq * 4)      = make_float4(o[0], o[1], o[2], o[3]);
      *(float4*)(Ab + (size_t)r * 128 + 64 + tq * 4) = make_float4(o[4], o[5], o[6], o[7]);
    }
  } else {
    // ------------------- layer-1 gemm: out = x@W + bias (R11 body) --------
    const int g = bid - 256;
    const int rb = g >> 1, cb = g & 1;
    const int m0 = rb * 128, c0 = cb * 128;

    float acc[8][8];
    #pragma unroll
    for (int j = 0; j < 8; ++j) {
      const int cj = (j < 4) ? (tq * 4 + j) : (64 + tq * 4 + (j - 4));
      const float bj = bias[c0 + cj];
      #pragma unroll
      for (int i = 0; i < 8; ++i) acc[i][j] = bj;
    }

    for (int kc = 0; kc < 16; ++kc) {
      __syncthreads();
      #pragma unroll
      for (int l = 0; l < 2; ++l) {   // stage A tile: 128 rows x 16 k
        const int f = t + 256 * l;
        const int row = f >> 2, k4 = (f & 3) * 4;
        const float4 a4 = *(const float4*)(x + (size_t)(m0 + row) * 256 + kc * 16 + k4);
        smem[GE_AS + (k4 + 0) * 132 + row] = a4.x;
        smem[GE_AS + (k4 + 1) * 132 + row] = a4.y;
        smem[GE_AS + (k4 + 2) * 132 + row] = a4.z;
        smem[GE_AS + (k4 + 3) * 132 + row] = a4.w;
      }
      #pragma unroll
      for (int l = 0; l < 2; ++l) {   // stage W tile: 16 k x 128 cols
        const int f = t + 256 * l;
        const int k = f >> 5, c4 = (f & 31) * 4;
        *(float4*)&smem[GE_WS + k * 132 + c4] =
            *(const float4*)(W + (size_t)(kc * 16 + k) * 256 + c0 + c4);
      }
      __syncthreads();
      #pragma unroll
      for (int k = 0; k < 16; ++k) {
        const float4 a0 = *(const float4*)&smem[GE_AS + k * 132 + tp * 4];
        const float4 a1 = *(const float4*)&smem[GE_AS + k * 132 + 64 + tp * 4];
        const float4 w0 = *(const float4*)&smem[GE_WS + k * 132 + tq * 4];
        const float4 w1 = *(const float4*)&smem[GE_WS + k * 132 + 64 + tq * 4];
        const float a[8] = {a0.x, a0.y, a0.z, a0.w, a1.x, a1.y, a1.z, a1.w};
        const float w[8] = {w0.x, w0.y, w0.z, w0.w, w1.x, w1.y, w1.z, w1.w};
        #pragma unroll
        for (int i = 0; i < 8; ++i)
          #pragma unroll
          for (int j = 0; j < 8; ++j) acc[i][j] += a[i] * w[j];
      }
    }

    #pragma unroll
    for (int i = 0; i < 8; ++i) {
      const int ri = (i < 4) ? (tp * 4 + i) : (64 + tp * 4 + (i - 4));
      float* orow = out + (size_t)(m0 + ri) * 256 + c0;
      *(float4*)(orow + tq * 4)      = make_float4(acc[i][0], acc[i][1], acc[i][2], acc[i][3]);
      *(float4*)(orow + 64 + tq * 4) = make_float4(acc[i][4], acc[i][5], acc[i][6], acc[i][7]);
    }
  }
}

// ---------------------------------------------------------------------------
// Tiled GEMM (layer 2) with (a) replicated BN scale/shift computed per block
// from the layer-1 stat partials (replaces k_bnscsh launch), (b) LDS
// DOUBLE-BUFFERED K-loop: one barrier per chunk, loads issued pre-barrier.
// FMA order unchanged (bias-first, ascending k).
// ---------------------------------------------------------------------------
__global__ __launch_bounds__(256) void k_gemmbn_t(
    const float* __restrict__ A, const float* __restrict__ part,
    const float* __restrict__ g, const float* __restrict__ be,
    const float* __restrict__ W, const float* __restrict__ bias,
    float* __restrict__ out) {
  __shared__ float As[2][16][132];
  __shared__ float Ws[2][16][132];
  __shared__ float scsh[512];
  const int rb = blockIdx.x, cb = blockIdx.y;
  const int t = threadIdx.x, tp = t >> 4, tq = t & 15;
  const int m0 = rb * 128, c0 = cb * 128;

  // replicated BN scale/shift (fixed serial order; deterministic)
  {
    const int ch = t, hb = ch >> 7, lc = ch & 127;
    float s = 0.f, q = 0.f;
    for (int u = 0; u < 256; ++u) {
      const float* pb = part + (size_t)(u * 2 + hb) * 256;
      s += pb[lc];
      q += pb[128 + lc];
    }
    const float m = s * (1.0f / 32768.0f);
    const float var = q * (1.0f / 32768.0f) - m * m;
    const float sc = g[ch] * rsqrtf(var + 1e-5f);
    scsh[ch] = sc;
    scsh[256 + ch] = be[ch] - m * sc;
  }

  float acc[8][8];
  #pragma unroll
  for (int j = 0; j < 8; ++j) {
    const int cj = (j < 4) ? (tq * 4 + j) : (64 + tq * 4 + (j - 4));
    const float bj = bias[c0 + cj];
    #pragma unroll
    for (int i = 0; i < 8; ++i) acc[i][j] = bj;
  }

  __syncthreads();   // scsh ready

  // prologue: load chunk 0, BN-apply, store into buffer 0
  float4 ra[2], rw[2];
  #pragma unroll
  for (int l = 0; l < 2; ++l) {
    const int f = t + 256 * l;
    const int row = f >> 2, k4 = (f & 3) * 4;
    ra[l] = *(const float4*)(A + (size_t)(m0 + row) * 256 + k4);
    const int kk = f >> 5, c4 = (f & 31) * 4;
    rw[l] = *(const float4*)(W + (size_t)kk * 256 + c0 + c4);
  }
  #pragma unroll
  for (int l = 0; l < 2; ++l) {
    const int f = t + 256 * l;
    const int row = f >> 2, k4 = (f & 3) * 4;
    const float4 sc = *(const float4*)&scsh[k4];
    const float4 sh = *(const float4*)&scsh[256 + k4];
    As[0][k4 + 0][row] = fmaxf(ra[l].x * sc.x + sh.x, 0.0f);
    As[0][k4 + 1][row] = fmaxf(ra[l].y * sc.y + sh.y, 0.0f);
    As[0][k4 + 2][row] = fmaxf(ra[l].z * sc.z + sh.z, 0.0f);
    As[0][k4 + 3][row] = fmaxf(ra[l].w * sc.w + sh.w, 0.0f);
    const int kk = f >> 5, c4 = (f & 31) * 4;
    *(float4*)&Ws[0][kk][c4] = rw[l];
  }

  for (int kc = 0; kc < 16; ++kc) {
    const int cur = kc & 1;
    if (kc < 15) {     // issue next-chunk loads before the barrier
      const int kn = (kc + 1) * 16;
      #pragma unroll
      for (int l = 0; l < 2; ++l) {
        const int f = t + 256 * l;
        const int row = f >> 2, k4 = (f & 3) * 4;
        ra[l] = *(const float4*)(A + (size_t)(m0 + row) * 256 + kn + k4);
        const int kk = f >> 5, c4 = (f & 31) * 4;
        rw[l] = *(const float4*)(W + (size_t)(kn + kk) * 256 + c0 + c4);
      }
    }
    __syncthreads();   // buf[cur] writes visible; buf[cur^1] fully consumed
    #pragma unroll
    for (int k = 0; k < 16; ++k) {
      const float4 a0 = *(const float4*)&As[cur][k][tp * 4];
      const float4 a1 = *(const float4*)&As[cur][k][64 + tp * 4];
      const float4 w0 = *(const float4*)&Ws[cur][k][tq * 4];
      const float4 w1 = *(const float4*)&Ws[cur][k][64 + tq * 4];
      const float a[8] = {a0.x, a0.y, a0.z, a0.w, a1.x, a1.y, a1.z, a1.w};
      const float w[8] = {w0.x, w0.y, w0.z, w0.w, w1.x, w1.y, w1.z, w1.w};
      #pragma unroll
      for (int i = 0; i < 8; ++i)
        #pragma unroll
        for (int j = 0; j < 8; ++j) acc[i][j] += a[i] * w[j];
    }
    if (kc < 15) {     // store next chunk into the other buffer
      const int kn = (kc + 1) * 16;
      #pragma unroll
      for (int l = 0; l < 2; ++l) {
        const int f = t + 256 * l;
        const int row = f >> 2, k4 = (f & 3) * 4;
        const float4 sc = *(const float4*)&scsh[kn + k4];
        const float4 sh = *(const float4*)&scsh[256 + kn + k4];
        As[cur ^ 1][k4 + 0][row] = fmaxf(ra[l].x * sc.x + sh.x, 0.0f);
        As[cur ^ 1][k4 + 1][row] = fmaxf(ra[l].y * sc.y + sh.y, 0.0f);
        As[cur ^ 1][k4 + 2][row] = fmaxf(ra[l].z * sc.z + sh.z, 0.0f);
        As[cur ^ 1][k4 + 3][row] = fmaxf(ra[l].w * sc.w + sh.w, 0.0f);
        const int kk = f >> 5, c4 = (f & 31) * 4;
        *(float4*)&Ws[cur ^ 1][kk][c4] = rw[l];
      }
    }
  }

  #pragma unroll
  for (int i = 0; i < 8; ++i) {
    const int ri = (i < 4) ? (tp * 4 + i) : (64 + tp * 4 + (i - 4));
    float* orow = out + (size_t)(m0 + ri) * 256 + c0;
    *(float4*)(orow + tq * 4)      = make_float4(acc[i][0], acc[i][1], acc[i][2], acc[i][3]);
    *(float4*)(orow + 64 + tq * 4) = make_float4(acc[i][4], acc[i][5], acc[i][6], acc[i][7]);
  }
}

// ---------------------------------------------------------------------------
// Tiled bmm + fused BN-stat partials. 128x128 tile, 8x8/thread, grid (256,2).
// Stats -> part[(blk*2+cb)*256 + {c | 128+c}]. (R11/R14 form — control.)
// ---------------------------------------------------------------------------
__global__ __launch_bounds__(256) void k_bmmst(
    const float* __restrict__ An, const float* __restrict__ XW,
    float* __restrict__ out, float* __restrict__ part) {
  __shared__ float As[16][132];   // [q][p]
  __shared__ float Ws[16][132];   // [q][c]
  __shared__ float rs[16][128];
  __shared__ float rq[16][128];
  const int blk = blockIdx.x, cb = blockIdx.y;
  const int t = threadIdx.x, tp = t >> 4, tq = t & 15;
  const float* Ab = An + (size_t)blk * 16384;        // [128][128]
  const float* Xb = XW + (size_t)blk * (128 * 256);  // [128][256]

  float acc[8][8];
  #pragma unroll
  for (int i = 0; i < 8; ++i)
    #pragma unroll
    for (int j = 0; j < 8; ++j) acc[i][j] = 0.f;

  for (int kc = 0; kc < 8; ++kc) {     // K=128, ascending q
    __syncthreads();
    #pragma unroll
    for (int l = 0; l < 2; ++l) {      // stage An tile: 128 p x 16 q
      const int f = t + 256 * l;
      const int row = f >> 2, k4 = (f & 3) * 4;
      const float4 a4 = *(const float4*)(Ab + (size_t)row * 128 + kc * 16 + k4);
      As[k4 + 0][row] = a4.x;
      As[k4 + 1][row] = a4.y;
      As[k4 + 2][row] = a4.z;
      As[k4 + 3][row] = a4.w;
    }
    #pragma unroll
    for (int l = 0; l < 2; ++l) {      // stage XW tile: 16 q x 128 c
      const int f = t + 256 * l;
      const int k = f >> 5, c4 = (f & 31) * 4;
      *(float4*)&Ws[k][c4] =
          *(const float4*)(Xb + (size_t)(kc * 16 + k) * 256 + cb * 128 + c4);
    }
    __syncthreads();
    #pragma unroll
    for (int k = 0; k < 16; ++k) {
      const float4 a0 = *(const float4*)&As[k][tp * 4];
      const float4 a1 = *(const float4*)&As[k][64 + tp * 4];
      const float4 w0 = *(const float4*)&Ws[k][tq * 4];
      const float4 w1 = *(const float4*)&Ws[k][64 + tq * 4];
      const float a[8] = {a0.x, a0.y, a0.z, a0.w, a1.x, a1.y, a1.z, a1.w};
      const float w[8] = {w0.x, w0.y, w0.z, w0.w, w1.x, w1.y, w1.z, w1.w};
      #pragma unroll
      for (int i = 0; i < 8; ++i)
        #pragma unroll
        for (int j = 0; j < 8; ++j) acc[i][j] += a[i] * w[j];
    }
  }

  // stats: per-thread col partial over 8 rows -> LDS -> 128-thread final
  #pragma unroll
  for (int j = 0; j < 8; ++j) {
    const int col = (j < 4) ? (tq * 4 + j) : (64 + tq * 4 + (j - 4));
    float cs = 0.f, cq = 0.f;
    #pragma unroll
    for (int i = 0; i < 8; ++i) { cs += acc[i][j]; cq += acc[i][j] * acc[i][j]; }
    rs[tp][col] = cs;
    rq[tp][col] = cq;
  }
  __syncthreads();
  if (t < 128) {
    float s = 0.f, q = 0.f;
    #pragma unroll
    for (int u = 0; u < 16; ++u) { s += rs[u][t]; q += rq[u][t]; }
    const int base = (blk * 2 + cb) * 256;
    part[base + t]       = s;
    part[base + 128 + t] = q;
  }

  #pragma unroll
  for (int i = 0; i < 8; ++i) {
    const int ri = (i < 4) ? (tp * 4 + i) : (64 + tp * 4 + (i - 4));
    float* orow = out + (size_t)(blk * 128 + ri) * 256 + cb * 128;
    *(float4*)(orow + tq * 4)      = make_float4(acc[i][0], acc[i][1], acc[i][2], acc[i][3]);
    *(float4*)(orow + 64 + tq * 4) = make_float4(acc[i][4], acc[i][5], acc[i][6], acc[i][7]);
  }
}

// ---------------------------------------------------------------------------
// head split-K GEMM v3 with replicated per-half BN scale/shift (replaces the
// second k_bnscsh launch). 1024 blocks (K-chunk 128) x 256 thr.
// ---------------------------------------------------------------------------
__global__ __launch_bounds__(256) void k_headgemm_v3(
    const float* __restrict__ pre2, const float* __restrict__ part,
    const float* __restrict__ g, const float* __restrict__ be,
    const float* __restrict__ Wm1, float* __restrict__ partout) {
  __shared__ float graphS[64][128];   // 32 KB
  __shared__ float scshh[256];        // [0..127]=sc, [128..255]=sh (this half)
  const int t = threadIdx.x;
  const int bid = blockIdx.x;
  const int k0 = bid * 128;
  const int cbase = k0 & 255;

  if (t < 128) {   // replicated BN scale/shift for this channel half
    const int ch = cbase + t, hb = ch >> 7, lc = ch & 127;
    float s = 0.f, q = 0.f;
    for (int u = 0; u < 256; ++u) {
      const float* pb = part + (size_t)(u * 2 + hb) * 256;
      s += pb[lc];
      q += pb[128 + lc];
    }
    const float m = s * (1.0f / 32768.0f);
    const float var = q * (1.0f / 32768.0f) - m * m;
    const float sc = g[ch] * rsqrtf(var + 1e-5f);
    scshh[t] = sc;
    scshh[128 + t] = be[ch] - m * sc;
  }
  __syncthreads();

  #pragma unroll
  for (int l = 0; l < 8; ++l) {
    const int f = t + 256 * l;
    const int row = f >> 5, c4 = (f & 31) * 4;
    const float4 p = *(const float4*)(pre2 + (size_t)row * FEAT_ + k0 + c4);
    const float4 sc = *(const float4*)&scshh[c4];
    const float4 sh = *(const float4*)&scshh[128 + c4];
    graphS[row][c4 + 0] = fmaxf(p.x * sc.x + sh.x, 0.0f);
    graphS[row][c4 + 1] = fmaxf(p.y * sc.y + sh.y, 0.0f);
    graphS[row][c4 + 2] = fmaxf(p.z * sc.z + sh.z, 0.0f);
    graphS[row][c4 + 3] = fmaxf(p.w * sc.w + sh.w, 0.0f);
  }
  __syncthreads();

  const int hg = t & 31;
  const int bg = t >> 5;
  float acc[8][4];
  #pragma unroll
  for (int i = 0; i < 8; ++i)
    #pragma unroll
    for (int j = 0; j < 4; ++j) acc[i][j] = 0.f;

  #pragma unroll 2
  for (int kk = 0; kk < 128; kk += 4) {
    const int k = k0 + kk;
    const float4 w0 = *(const float4*)(Wm1 + (size_t)(k + 0) * 128 + hg * 4);
    const float4 w1 = *(const float4*)(Wm1 + (size_t)(k + 1) * 128 + hg * 4);
    const float4 w2 = *(const float4*)(Wm1 + (size_t)(k + 2) * 128 + hg * 4);
    const float4 w3 = *(const float4*)(Wm1 + (size_t)(k + 3) * 128 + hg * 4);
    #pragma unroll
    for (int i = 0; i < 8; ++i) {
      const float4 a = *(const float4*)&graphS[bg * 8 + i][kk];
      acc[i][0] += a.x * w0.x; acc[i][1] += a.x * w0.y;
      acc[i][2] += a.x * w0.z; acc[i][3] += a.x * w0.w;
      acc[i][0] += a.y * w1.x; acc[i][1] += a.y * w1.y;
      acc[i][2] += a.y * w1.z; acc[i][3] += a.y * w1.w;
      acc[i][0] += a.z * w2.x; acc[i][1] += a.z * w2.y;
      acc[i][2] += a.z * w2.z; acc[i][3] += a.z * w2.w;
      acc[i][0] += a.w * w3.x; acc[i][1] += a.w * w3.y;
      acc[i][2] += a.w * w3.z; acc[i][3] += a.w * w3.w;
    }
  }

  float* pb = partout + (size_t)bid * 8192;
  #pragma unroll
  for (int i = 0; i < 8; ++i)
    *(float4*)(pb + (bg * 8 + i) * 128 + hg * 4) =
        make_float4(acc[i][0], acc[i][1], acc[i][2], acc[i][3]);
}

// ---------------------------------------------------------------------------
// head reduce stage A: part2[jg][o] = sum of 128 consecutive partials.
// ---------------------------------------------------------------------------
__global__ __launch_bounds__(256) void k_headredA(
    const float* __restrict__ part, float* __restrict__ part2) {
  const int o = blockIdx.x * 256 + threadIdx.x;
  const int jg = blockIdx.y;
  const float* base = part + (size_t)jg * 128 * 8192;
  float s = 0.f;
  for (int j = 0; j < 128; ++j) s += base[(size_t)j * 8192 + o];
  part2[(size_t)jg * 8192 + o] = s;
}

// ---------------------------------------------------------------------------
// Fused head tail: z1 reduce -> BN1+ReLU -> mm2 -> BN2+ReLU -> out.
// ONE block, 256 threads, everything in LDS. (R10/R14-verified form.)
// ---------------------------------------------------------------------------
__global__ __launch_bounds__(256) void k_headtail(
    const float* __restrict__ part2,
    const float* __restrict__ gm1, const float* __restrict__ bem1,
    const float* __restrict__ Wm2,
    const float* __restrict__ gm2, const float* __restrict__ bem2,
    const float* __restrict__ Wm3, const float* __restrict__ bm3,
    float* __restrict__ out) {
  __shared__ float zs[8192];     // z1 / zr1 (64x128)
  __shared__ float wm2s[8192];   // Wm2 (128x64)
  __shared__ float zb2[4096];    // z2 / zr2 (64x64)
  __shared__ float sc1[128], sh1[128], sc2[64], sh2[64];
  const int t = threadIdx.x;

  for (int o = t; o < 8192; o += 256) {
    float s = 0.f;
    #pragma unroll
    for (int jg = 0; jg < 8; ++jg) s += part2[(size_t)jg * 8192 + o];
    zs[o] = s;
  }
  for (int o = t; o < 8192; o += 256) wm2s[o] = Wm2[o];
  __syncthreads();

  if (t < 128) {
    float s = 0.f, q = 0.f;
    for (int b = 0; b < 64; ++b) { const float v = zs[b * 128 + t]; s += v; q += v * v; }
    const float m = s * (1.0f / 64.0f);
    const float var = q * (1.0f / 64.0f) - m * m;
    const float sc = gm1[t] * rsqrtf(var + 1e-5f);
    sc1[t] = sc; sh1[t] = bem1[t] - m * sc;
  }
  __syncthreads();
  for (int o = t; o < 8192; o += 256)
    zs[o] = fmaxf(zs[o] * sc1[o & 127] + sh1[o & 127], 0.0f);
  __syncthreads();

  {
    const int bq = t >> 4, jq = t & 15;
    float acc[4][4];
    #pragma unroll
    for (int bi = 0; bi < 4; ++bi)
      #pragma unroll
      for (int ji = 0; ji < 4; ++ji) acc[bi][ji] = 0.f;
    for (int k = 0; k < 128; ++k) {
      const float4 w4 = *(const float4*)&wm2s[k * 64 + jq * 4];
      const float wv[4] = {w4.x, w4.y, w4.z, w4.w};
      #pragma unroll
      for (int bi = 0; bi < 4; ++bi) {
        const float zv = zs[(bq * 4 + bi) * 128 + k];
        #pragma unroll
        for (int ji = 0; ji < 4; ++ji) acc[bi][ji] += zv * wv[ji];
      }
    }
    #pragma unroll
    for (int bi = 0; bi < 4; ++bi)
      #pragma unroll
      for (int ji = 0; ji < 4; ++ji)
        zb2[(bq * 4 + bi) * 64 + jq * 4 + ji] = acc[bi][ji];
  }
  __syncthreads();

  if (t < 64) {
    float s = 0.f, q = 0.f;
    for (int b = 0; b < 64; ++b) { const float v = zb2[b * 64 + t]; s += v; q += v * v; }
    const float m = s * (1.0f / 64.0f);
    const float var = q * (1.0f / 64.0f) - m * m;
    const float sc = gm2[t] * rsqrtf(var + 1e-5f);
    sc2[t] = sc; sh2[t] = bem2[t] - m * sc;
  }
  __syncthreads();
  for (int idx = t; idx < 4096; idx += 256)
    zb2[idx] = fmaxf(zb2[idx] * sc2[idx & 63] + sh2[idx & 63], 0.0f);
  __syncthreads();

  if (t < 128) {
    const int b = t >> 1, c = t & 1;
    float s = bm3[c];
    for (int k = 0; k < 64; ++k) s += zb2[b * 64 + k] * Wm3[k * 2 + c];
    out[t] = s;
  }
}

// ---------------------------------------------------------------------------
extern "C" void kernel_launch(void* const* d_in, const int* in_sizes, int n_in,
                              void* d_out, int out_size, void* d_ws, size_t ws_size,
                              hipStream_t stream) {
  (void)in_sizes; (void)n_in; (void)out_size; (void)ws_size;
  const float* x    = (const float*)d_in[0];
  const float* mask = (const float*)d_in[1];
  const float* W1   = (const float*)d_in[2];
  const float* b1   = (const float*)d_in[3];
  const float* g1   = (const float*)d_in[4];
  const float* be1  = (const float*)d_in[5];
  const float* W2   = (const float*)d_in[6];
  const float* b2   = (const float*)d_in[7];
  const float* g2   = (const float*)d_in[8];
  const float* be2  = (const float*)d_in[9];
  const float* Wm1  = (const float*)d_in[10];
  // d_in[11] = bm1 (zeros; cancels under BN)
  const float* gm1  = (const float*)d_in[12];
  const float* bem1 = (const float*)d_in[13];
  const float* Wm2  = (const float*)d_in[14];
  // d_in[15] = bm2 (zeros; cancels under BN)
  const float* gm2  = (const float*)d_in[16];
  const float* bem2 = (const float*)d_in[17];
  const float* Wm3  = (const float*)d_in[18];
  const float* bm3  = (const float*)d_in[19];

  // workspace (floats), same extent as verified previously (117.67 MB)
  float* ws   = (float*)d_ws;
  float* T1   = ws;                 // 8,388,608 : bn-stat partials
  float* An   = T1 + 8388608;       // 4,194,304 : An -> head part2
  float* T2   = An + 4194304;       // 8,388,608 : XW1 -> XW2 -> head partials
  float* T3   = T2 + 8388608;       // 8,388,608 : pre1 -> pre2

  // fused independent stages: sim->An (blocks 0..255) + gemm1->T2 (256..767)
  k_simgemm<<<768, 256, 0, stream>>>(x, mask, An, W1, b1, T2);

  // layer 1 rest: pre1 = An @ XW1 (T3); stats -> T1
  k_bmmst<<<dim3(256, 2), 256, 0, stream>>>(An, T2, T3, T1);

  // layer 2: XW2 = relu(bn(pre1))@W2+b2 (stats replicated in-kernel), then
  // pre2 = An @ XW2; stats -> T1
  k_gemmbn_t<<<dim3(256, 2), 256, 0, stream>>>(T3, T1, g1, be1, W2, b2, T2);
  k_bmmst<<<dim3(256, 2), 256, 0, stream>>>(An, T2, T3, T1);

  // head: z1 = relu(bn(pre2)) @ Wm1 (stats replicated), split-K + reduce + tail
  k_headgemm_v3<<<1024, 256, 0, stream>>>(T3, T1, g2, be2, Wm1, T2);
  k_headredA<<<dim3(32, 8), 256, 0, stream>>>(T2, An);
  k_headtail<<<1, 256, 0, stream>>>(An, gm1, bem1, Wm2, gm2, bem2,
                                    Wm3, bm3, (float*)d_out);
}

// Round 16
// 414.220 us; speedup vs baseline: 1.1105x; 1.1105x over previous
//
#include <hip/hip_runtime.h>
#include <cstdint>
#include <cstddef>

// Shapes (fixed): B=64, N=4, P=128, d=h=256, totP=512, feat=131072
#define P_    128
#define H_    256
#define FEAT_ 131072

// ---------------------------------------------------------------------------
// FUSED independent-stage kernel: blocks 0..255 run the sim+deg+normalize
// body (-> An); blocks 256..767 run layer-1 gemm (x@W1+b1 -> XW1).
// Sim body in the conflict-free 4-split fragment layout (pad 132).
// (R15-verified numerics.)
// ---------------------------------------------------------------------------
#define SIM_XS   0      // [16][132] = 2112
#define SIM_RED  2112   // [128][17] = 2176
#define SIM_DIAG 4288   // 128
#define SIM_INV  4416   // 128
#define SIM_DINV 4544   // 128  (total 4672)
#define GE_AS    0      // [16][132] = 2112
#define GE_WS    2112   // [16][132] = 2112 (total 4224)

__global__ __launch_bounds__(256) void k_simgemm(
    const float* __restrict__ x, const float* __restrict__ mask,
    float* __restrict__ An,
    const float* __restrict__ W, const float* __restrict__ bias,
    float* __restrict__ out) {
  __shared__ float smem[4672];
  const int bid = blockIdx.x;
  const int t = threadIdx.x, tp = t >> 4, tq = t & 15;

  if (bid < 256) {
    // ------------- sim + deg + sym-normalize (4-split retile) -------------
    const int blk = bid;
    const float* Xb = x + (size_t)blk * (128 * 256);

    float v[8][8];
    #pragma unroll
    for (int i = 0; i < 8; ++i)
      #pragma unroll
      for (int j = 0; j < 8; ++j) v[i][j] = 0.f;

    for (int kc = 0; kc < 16; ++kc) {
      __syncthreads();
      #pragma unroll
      for (int l = 0; l < 2; ++l) {
        const int f = t + 256 * l;
        const int row = f >> 2, k4 = (f & 3) * 4;
        const float4 x4 = *(const float4*)(Xb + (size_t)row * 256 + kc * 16 + k4);
        smem[SIM_XS + (k4 + 0) * 132 + row] = x4.x;
        smem[SIM_XS + (k4 + 1) * 132 + row] = x4.y;
        smem[SIM_XS + (k4 + 2) * 132 + row] = x4.z;
        smem[SIM_XS + (k4 + 3) * 132 + row] = x4.w;
      }
      __syncthreads();
      #pragma unroll
      for (int k = 0; k < 16; ++k) {
        const float4 a0 = *(const float4*)&smem[SIM_XS + k * 132 + tp * 4];
        const float4 a1 = *(const float4*)&smem[SIM_XS + k * 132 + 64 + tp * 4];
        const float4 b0 = *(const float4*)&smem[SIM_XS + k * 132 + tq * 4];
        const float4 b1 = *(const float4*)&smem[SIM_XS + k * 132 + 64 + tq * 4];
        const float a[8] = {a0.x, a0.y, a0.z, a0.w, a1.x, a1.y, a1.z, a1.w};
        const float b[8] = {b0.x, b0.y, b0.z, b0.w, b1.x, b1.y, b1.z, b1.w};
        #pragma unroll
        for (int i = 0; i < 8; ++i)
          #pragma unroll
          for (int j = 0; j < 8; ++j) v[i][j] += a[i] * b[j];
      }
    }

    if (tp == tq) {
      #pragma unroll
      for (int i = 0; i < 8; ++i) {
        const int r = (i < 4) ? (tp * 4 + i) : (64 + tp * 4 + (i - 4));
        smem[SIM_DIAG + r] = v[i][i];
      }
    }
    __syncthreads();
    if (t < 128)
      smem[SIM_INV + t] = 1.0f / fmaxf(sqrtf(smem[SIM_DIAG + t]), 1e-12f);
    __syncthreads();

    float ivq[8];
    #pragma unroll
    for (int j = 0; j < 8; ++j) {
      const int c = (j < 4) ? (tq * 4 + j) : (64 + tq * 4 + (j - 4));
      ivq[j] = smem[SIM_INV + c];
    }

    #pragma unroll
    for (int i = 0; i < 8; ++i) {
      const int r = (i < 4) ? (tp * 4 + i) : (64 + tp * 4 + (i - 4));
      const float ivp = smem[SIM_INV + r];
      const float4 m0 = *(const float4*)(mask + r * 128 + tq * 4);
      const float4 m1 = *(const float4*)(mask + r * 128 + 64 + tq * 4);
      const float mm[8] = {m0.x, m0.y, m0.z, m0.w, m1.x, m1.y, m1.z, m1.w};
      float s = 0.f;
      #pragma unroll
      for (int j = 0; j < 8; ++j) {
        const int c = (j < 4) ? (tq * 4 + j) : (64 + tq * 4 + (j - 4));
        const float vv = (r == c) ? 0.0f
                                  : (v[i][j] * ivp * ivq[j] + 1.0f) * 0.5f * mm[j];
        v[i][j] = vv;
        s += vv;
      }
      smem[SIM_RED + r * 17 + tq] = s;
    }
    __syncthreads();
    if (t < 128) {
      float sm = 0.f;
      #pragma unroll
      for (int u = 0; u < 16; ++u) sm += smem[SIM_RED + t * 17 + u];
      const float deg = 1.0f + sm;
      smem[SIM_DINV + t] = (deg > 0.0f) ? rsqrtf(fmaxf(deg, 1e-12f)) : 0.0f;
    }
    __syncthreads();

    float dq[8];
    #pragma unroll
    for (int j = 0; j < 8; ++j) {
      const int c = (j < 4) ? (tq * 4 + j) : (64 + tq * 4 + (j - 4));
      dq[j] = smem[SIM_DINV + c];
    }
    float* Ab = An + (size_t)blk * 16384;
    #pragma unroll
    for (int i = 0; i < 8; ++i) {
      const int r = (i < 4) ? (tp * 4 + i) : (64 + tp * 4 + (i - 4));
      const float dp = smem[SIM_DINV + r];
      float o[8];
      #pragma unroll
      for (int j = 0; j < 8; ++j) {
        const int c = (j < 4) ? (tq * 4 + j) : (64 + tq * 4 + (j - 4));
        o[j] = (r == c) ? dp * dq[j] : v[i][j] * dp * dq[j];
      }
      *(float4*)(Ab + (size_t)r * 128 + tq * 4)      = make_float4(o[0], o[1], o[2], o[3]);
      *(float4*)(Ab + (size_t)r * 128 + 64 + tq * 4) = make_float4(o[4], o[5], o[6], o[7]);
    }
  } else {
    // ------------------- layer-1 gemm: out = x@W + bias (R11 body) --------
    const int g = bid - 256;
    const int rb = g >> 1, cb = g & 1;
    const int m0 = rb * 128, c0 = cb * 128;

    float acc[8][8];
    #pragma unroll
    for (int j = 0; j < 8; ++j) {
      const int cj = (j < 4) ? (tq * 4 + j) : (64 + tq * 4 + (j - 4));
      const float bj = bias[c0 + cj];
      #pragma unroll
      for (int i = 0; i < 8; ++i) acc[i][j] = bj;
    }

    for (int kc = 0; kc < 16; ++kc) {
      __syncthreads();
      #pragma unroll
      for (int l = 0; l < 2; ++l) {   // stage A tile: 128 rows x 16 k
        const int f = t + 256 * l;
        const int row = f >> 2, k4 = (f & 3) * 4;
        const float4 a4 = *(const float4*)(x + (size_t)(m0 + row) * 256 + kc * 16 + k4);
        smem[GE_AS + (k4 + 0) * 132 + row] = a4.x;
        smem[GE_AS + (k4 + 1) * 132 + row] = a4.y;
        smem[GE_AS + (k4 + 2) * 132 + row] = a4.z;
        smem[GE_AS + (k4 + 3) * 132 + row] = a4.w;
      }
      #pragma unroll
      for (int l = 0; l < 2; ++l) {   // stage W tile: 16 k x 128 cols
        const int f = t + 256 * l;
        const int k = f >> 5, c4 = (f & 31) * 4;
        *(float4*)&smem[GE_WS + k * 132 + c4] =
            *(const float4*)(W + (size_t)(kc * 16 + k) * 256 + c0 + c4);
      }
      __syncthreads();
      #pragma unroll
      for (int k = 0; k < 16; ++k) {
        const float4 a0 = *(const float4*)&smem[GE_AS + k * 132 + tp * 4];
        const float4 a1 = *(const float4*)&smem[GE_AS + k * 132 + 64 + tp * 4];
        const float4 w0 = *(const float4*)&smem[GE_WS + k * 132 + tq * 4];
        const float4 w1 = *(const float4*)&smem[GE_WS + k * 132 + 64 + tq * 4];
        const float a[8] = {a0.x, a0.y, a0.z, a0.w, a1.x, a1.y, a1.z, a1.w};
        const float w[8] = {w0.x, w0.y, w0.z, w0.w, w1.x, w1.y, w1.z, w1.w};
        #pragma unroll
        for (int i = 0; i < 8; ++i)
          #pragma unroll
          for (int j = 0; j < 8; ++j) acc[i][j] += a[i] * w[j];
      }
    }

    #pragma unroll
    for (int i = 0; i < 8; ++i) {
      const int ri = (i < 4) ? (tp * 4 + i) : (64 + tp * 4 + (i - 4));
      float* orow = out + (size_t)(m0 + ri) * 256 + c0;
      *(float4*)(orow + tq * 4)      = make_float4(acc[i][0], acc[i][1], acc[i][2], acc[i][3]);
      *(float4*)(orow + 64 + tq * 4) = make_float4(acc[i][4], acc[i][5], acc[i][6], acc[i][7]);
    }
  }
}

// ---------------------------------------------------------------------------
// Tiled GEMM (layer 2): R11-verified SINGLE-buffer loop (dbuf reverted —
// R15 showed it costs VGPR 188 / LDS 36KB -> 11% occupancy, 2x slower).
// Keeps the replicated BN scale/shift prologue (replaces k_bnscsh launch).
// ---------------------------------------------------------------------------
__global__ __launch_bounds__(256) void k_gemmbn_t(
    const float* __restrict__ A, const float* __restrict__ part,
    const float* __restrict__ g, const float* __restrict__ be,
    const float* __restrict__ W, const float* __restrict__ bias,
    float* __restrict__ out) {
  __shared__ float As[16][132];
  __shared__ float Ws[16][132];
  __shared__ float scsh[512];
  const int rb = blockIdx.x, cb = blockIdx.y;
  const int t = threadIdx.x, tp = t >> 4, tq = t & 15;
  const int m0 = rb * 128, c0 = cb * 128;

  // replicated BN scale/shift (fixed serial order; deterministic)
  {
    const int ch = t, hb = ch >> 7, lc = ch & 127;
    float s = 0.f, q = 0.f;
    for (int u = 0; u < 256; ++u) {
      const float* pb = part + (size_t)(u * 2 + hb) * 256;
      s += pb[lc];
      q += pb[128 + lc];
    }
    const float m = s * (1.0f / 32768.0f);
    const float var = q * (1.0f / 32768.0f) - m * m;
    const float sc = g[ch] * rsqrtf(var + 1e-5f);
    scsh[ch] = sc;
    scsh[256 + ch] = be[ch] - m * sc;
  }

  float acc[8][8];
  #pragma unroll
  for (int j = 0; j < 8; ++j) {
    const int cj = (j < 4) ? (tq * 4 + j) : (64 + tq * 4 + (j - 4));
    const float bj = bias[c0 + cj];
    #pragma unroll
    for (int i = 0; i < 8; ++i) acc[i][j] = bj;
  }
  __syncthreads();   // scsh ready

  for (int kc = 0; kc < 16; ++kc) {
    __syncthreads();
    #pragma unroll
    for (int l = 0; l < 2; ++l) {   // stage A tile with BN+ReLU (chan = k)
      const int f = t + 256 * l;
      const int row = f >> 2, k4 = (f & 3) * 4;
      const int col = kc * 16 + k4;
      const float4 a4 = *(const float4*)(A + (size_t)(m0 + row) * 256 + col);
      const float4 sc = *(const float4*)&scsh[col];
      const float4 sh = *(const float4*)&scsh[256 + col];
      As[k4 + 0][row] = fmaxf(a4.x * sc.x + sh.x, 0.0f);
      As[k4 + 1][row] = fmaxf(a4.y * sc.y + sh.y, 0.0f);
      As[k4 + 2][row] = fmaxf(a4.z * sc.z + sh.z, 0.0f);
      As[k4 + 3][row] = fmaxf(a4.w * sc.w + sh.w, 0.0f);
    }
    #pragma unroll
    for (int l = 0; l < 2; ++l) {
      const int f = t + 256 * l;
      const int k = f >> 5, c4 = (f & 31) * 4;
      *(float4*)&Ws[k][c4] =
          *(const float4*)(W + (size_t)(kc * 16 + k) * 256 + c0 + c4);
    }
    __syncthreads();
    #pragma unroll
    for (int k = 0; k < 16; ++k) {
      const float4 a0 = *(const float4*)&As[k][tp * 4];
      const float4 a1 = *(const float4*)&As[k][64 + tp * 4];
      const float4 w0 = *(const float4*)&Ws[k][tq * 4];
      const float4 w1 = *(const float4*)&Ws[k][64 + tq * 4];
      const float a[8] = {a0.x, a0.y, a0.z, a0.w, a1.x, a1.y, a1.z, a1.w};
      const float w[8] = {w0.x, w0.y, w0.z, w0.w, w1.x, w1.y, w1.z, w1.w};
      #pragma unroll
      for (int i = 0; i < 8; ++i)
        #pragma unroll
        for (int j = 0; j < 8; ++j) acc[i][j] += a[i] * w[j];
    }
  }

  #pragma unroll
  for (int i = 0; i < 8; ++i) {
    const int ri = (i < 4) ? (tp * 4 + i) : (64 + tp * 4 + (i - 4));
    float* orow = out + (size_t)(m0 + ri) * 256 + c0;
    *(float4*)(orow + tq * 4)      = make_float4(acc[i][0], acc[i][1], acc[i][2], acc[i][3]);
    *(float4*)(orow + 64 + tq * 4) = make_float4(acc[i][4], acc[i][5], acc[i][6], acc[i][7]);
  }
}

// ---------------------------------------------------------------------------
// Tiled bmm + fused BN-stat partials. 128x128 tile, 8x8/thread, grid (256,2).
// Stats -> part[(blk*2+cb)*256 + {c | 128+c}]. (R11/R14 form.)
// ---------------------------------------------------------------------------
__global__ __launch_bounds__(256) void k_bmmst(
    const float* __restrict__ An, const float* __restrict__ XW,
    float* __restrict__ out, float* __restrict__ part) {
  __shared__ float As[16][132];   // [q][p]
  __shared__ float Ws[16][132];   // [q][c]
  __shared__ float rs[16][128];
  __shared__ float rq[16][128];
  const int blk = blockIdx.x, cb = blockIdx.y;
  const int t = threadIdx.x, tp = t >> 4, tq = t & 15;
  const float* Ab = An + (size_t)blk * 16384;        // [128][128]
  const float* Xb = XW + (size_t)blk * (128 * 256);  // [128][256]

  float acc[8][8];
  #pragma unroll
  for (int i = 0; i < 8; ++i)
    #pragma unroll
    for (int j = 0; j < 8; ++j) acc[i][j] = 0.f;

  for (int kc = 0; kc < 8; ++kc) {     // K=128, ascending q
    __syncthreads();
    #pragma unroll
    for (int l = 0; l < 2; ++l) {      // stage An tile: 128 p x 16 q
      const int f = t + 256 * l;
      const int row = f >> 2, k4 = (f & 3) * 4;
      const float4 a4 = *(const float4*)(Ab + (size_t)row * 128 + kc * 16 + k4);
      As[k4 + 0][row] = a4.x;
      As[k4 + 1][row] = a4.y;
      As[k4 + 2][row] = a4.z;
      As[k4 + 3][row] = a4.w;
    }
    #pragma unroll
    for (int l = 0; l < 2; ++l) {      // stage XW tile: 16 q x 128 c
      const int f = t + 256 * l;
      const int k = f >> 5, c4 = (f & 31) * 4;
      *(float4*)&Ws[k][c4] =
          *(const float4*)(Xb + (size_t)(kc * 16 + k) * 256 + cb * 128 + c4);
    }
    __syncthreads();
    #pragma unroll
    for (int k = 0; k < 16; ++k) {
      const float4 a0 = *(const float4*)&As[k][tp * 4];
      const float4 a1 = *(const float4*)&As[k][64 + tp * 4];
      const float4 w0 = *(const float4*)&Ws[k][tq * 4];
      const float4 w1 = *(const float4*)&Ws[k][64 + tq * 4];
      const float a[8] = {a0.x, a0.y, a0.z, a0.w, a1.x, a1.y, a1.z, a1.w};
      const float w[8] = {w0.x, w0.y, w0.z, w0.w, w1.x, w1.y, w1.z, w1.w};
      #pragma unroll
      for (int i = 0; i < 8; ++i)
        #pragma unroll
        for (int j = 0; j < 8; ++j) acc[i][j] += a[i] * w[j];
    }
  }

  // stats: per-thread col partial over 8 rows -> LDS -> 128-thread final
  #pragma unroll
  for (int j = 0; j < 8; ++j) {
    const int col = (j < 4) ? (tq * 4 + j) : (64 + tq * 4 + (j - 4));
    float cs = 0.f, cq = 0.f;
    #pragma unroll
    for (int i = 0; i < 8; ++i) { cs += acc[i][j]; cq += acc[i][j] * acc[i][j]; }
    rs[tp][col] = cs;
    rq[tp][col] = cq;
  }
  __syncthreads();
  if (t < 128) {
    float s = 0.f, q = 0.f;
    #pragma unroll
    for (int u = 0; u < 16; ++u) { s += rs[u][t]; q += rq[u][t]; }
    const int base = (blk * 2 + cb) * 256;
    part[base + t]       = s;
    part[base + 128 + t] = q;
  }

  #pragma unroll
  for (int i = 0; i < 8; ++i) {
    const int ri = (i < 4) ? (tp * 4 + i) : (64 + tp * 4 + (i - 4));
    float* orow = out + (size_t)(blk * 128 + ri) * 256 + cb * 128;
    *(float4*)(orow + tq * 4)      = make_float4(acc[i][0], acc[i][1], acc[i][2], acc[i][3]);
    *(float4*)(orow + 64 + tq * 4) = make_float4(acc[i][4], acc[i][5], acc[i][6], acc[i][7]);
  }
}

// ---------------------------------------------------------------------------
// head split-K GEMM v3 with replicated per-half BN scale/shift.
// 1024 blocks (K-chunk 128) x 256 thr. (R15-verified numerics.)
// ---------------------------------------------------------------------------
__global__ __launch_bounds__(256) void k_headgemm_v3(
    const float* __restrict__ pre2, const float* __restrict__ part,
    const float* __restrict__ g, const float* __restrict__ be,
    const float* __restrict__ Wm1, float* __restrict__ partout) {
  __shared__ float graphS[64][128];   // 32 KB
  __shared__ float scshh[256];        // [0..127]=sc, [128..255]=sh (this half)
  const int t = threadIdx.x;
  const int bid = blockIdx.x;
  const int k0 = bid * 128;
  const int cbase = k0 & 255;

  if (t < 128) {   // replicated BN scale/shift for this channel half
    const int ch = cbase + t, hb = ch >> 7, lc = ch & 127;
    float s = 0.f, q = 0.f;
    for (int u = 0; u < 256; ++u) {
      const float* pb = part + (size_t)(u * 2 + hb) * 256;
      s += pb[lc];
      q += pb[128 + lc];
    }
    const float m = s * (1.0f / 32768.0f);
    const float var = q * (1.0f / 32768.0f) - m * m;
    const float sc = g[ch] * rsqrtf(var + 1e-5f);
    scshh[t] = sc;
    scshh[128 + t] = be[ch] - m * sc;
  }
  __syncthreads();

  #pragma unroll
  for (int l = 0; l < 8; ++l) {
    const int f = t + 256 * l;
    const int row = f >> 5, c4 = (f & 31) * 4;
    const float4 p = *(const float4*)(pre2 + (size_t)row * FEAT_ + k0 + c4);
    const float4 sc = *(const float4*)&scshh[c4];
    const float4 sh = *(const float4*)&scshh[128 + c4];
    graphS[row][c4 + 0] = fmaxf(p.x * sc.x + sh.x, 0.0f);
    graphS[row][c4 + 1] = fmaxf(p.y * sc.y + sh.y, 0.0f);
    graphS[row][c4 + 2] = fmaxf(p.z * sc.z + sh.z, 0.0f);
    graphS[row][c4 + 3] = fmaxf(p.w * sc.w + sh.w, 0.0f);
  }
  __syncthreads();

  const int hg = t & 31;
  const int bg = t >> 5;
  float acc[8][4];
  #pragma unroll
  for (int i = 0; i < 8; ++i)
    #pragma unroll
    for (int j = 0; j < 4; ++j) acc[i][j] = 0.f;

  #pragma unroll 2
  for (int kk = 0; kk < 128; kk += 4) {
    const int k = k0 + kk;
    const float4 w0 = *(const float4*)(Wm1 + (size_t)(k + 0) * 128 + hg * 4);
    const float4 w1 = *(const float4*)(Wm1 + (size_t)(k + 1) * 128 + hg * 4);
    const float4 w2 = *(const float4*)(Wm1 + (size_t)(k + 2) * 128 + hg * 4);
    const float4 w3 = *(const float4*)(Wm1 + (size_t)(k + 3) * 128 + hg * 4);
    #pragma unroll
    for (int i = 0; i < 8; ++i) {
      const float4 a = *(const float4*)&graphS[bg * 8 + i][kk];
      acc[i][0] += a.x * w0.x; acc[i][1] += a.x * w0.y;
      acc[i][2] += a.x * w0.z; acc[i][3] += a.x * w0.w;
      acc[i][0] += a.y * w1.x; acc[i][1] += a.y * w1.y;
      acc[i][2] += a.y * w1.z; acc[i][3] += a.y * w1.w;
      acc[i][0] += a.z * w2.x; acc[i][1] += a.z * w2.y;
      acc[i][2] += a.z * w2.z; acc[i][3] += a.z * w2.w;
      acc[i][0] += a.w * w3.x; acc[i][1] += a.w * w3.y;
      acc[i][2] += a.w * w3.z; acc[i][3] += a.w * w3.w;
    }
  }

  float* pb = partout + (size_t)bid * 8192;
  #pragma unroll
  for (int i = 0; i < 8; ++i)
    *(float4*)(pb + (bg * 8 + i) * 128 + hg * 4) =
        make_float4(acc[i][0], acc[i][1], acc[i][2], acc[i][3]);
}

// ---------------------------------------------------------------------------
// head reduce stage A: part2[jg][o] = sum of 128 consecutive partials.
// ---------------------------------------------------------------------------
__global__ __launch_bounds__(256) void k_headredA(
    const float* __restrict__ part, float* __restrict__ part2) {
  const int o = blockIdx.x * 256 + threadIdx.x;
  const int jg = blockIdx.y;
  const float* base = part + (size_t)jg * 128 * 8192;
  float s = 0.f;
  for (int j = 0; j < 128; ++j) s += base[(size_t)j * 8192 + o];
  part2[(size_t)jg * 8192 + o] = s;
}

// ---------------------------------------------------------------------------
// Fused head tail: z1 reduce -> BN1+ReLU -> mm2 -> BN2+ReLU -> out.
// ONE block, 256 threads, everything in LDS. (R10/R14-verified form.)
// ---------------------------------------------------------------------------
__global__ __launch_bounds__(256) void k_headtail(
    const float* __restrict__ part2,
    const float* __restrict__ gm1, const float* __restrict__ bem1,
    const float* __restrict__ Wm2,
    const float* __restrict__ gm2, const float* __restrict__ bem2,
    const float* __restrict__ Wm3, const float* __restrict__ bm3,
    float* __restrict__ out) {
  __shared__ float zs[8192];     // z1 / zr1 (64x128)
  __shared__ float wm2s[8192];   // Wm2 (128x64)
  __shared__ float zb2[4096];    // z2 / zr2 (64x64)
  __shared__ float sc1[128], sh1[128], sc2[64], sh2[64];
  const int t = threadIdx.x;

  for (int o = t; o < 8192; o += 256) {
    float s = 0.f;
    #pragma unroll
    for (int jg = 0; jg < 8; ++jg) s += part2[(size_t)jg * 8192 + o];
    zs[o] = s;
  }
  for (int o = t; o < 8192; o += 256) wm2s[o] = Wm2[o];
  __syncthreads();

  if (t < 128) {
    float s = 0.f, q = 0.f;
    for (int b = 0; b < 64; ++b) { const float v = zs[b * 128 + t]; s += v; q += v * v; }
    const float m = s * (1.0f / 64.0f);
    const float var = q * (1.0f / 64.0f) - m * m;
    const float sc = gm1[t] * rsqrtf(var + 1e-5f);
    sc1[t] = sc; sh1[t] = bem1[t] - m * sc;
  }
  __syncthreads();
  for (int o = t; o < 8192; o += 256)
    zs[o] = fmaxf(zs[o] * sc1[o & 127] + sh1[o & 127], 0.0f);
  __syncthreads();

  {
    const int bq = t >> 4, jq = t & 15;
    float acc[4][4];
    #pragma unroll
    for (int bi = 0; bi < 4; ++bi)
      #pragma unroll
      for (int ji = 0; ji < 4; ++ji) acc[bi][ji] = 0.f;
    for (int k = 0; k < 128; ++k) {
      const float4 w4 = *(const float4*)&wm2s[k * 64 + jq * 4];
      const float wv[4] = {w4.x, w4.y, w4.z, w4.w};
      #pragma unroll
      for (int bi = 0; bi < 4; ++bi) {
        const float zv = zs[(bq * 4 + bi) * 128 + k];
        #pragma unroll
        for (int ji = 0; ji < 4; ++ji) acc[bi][ji] += zv * wv[ji];
      }
    }
    #pragma unroll
    for (int bi = 0; bi < 4; ++bi)
      #pragma unroll
      for (int ji = 0; ji < 4; ++ji)
        zb2[(bq * 4 + bi) * 64 + jq * 4 + ji] = acc[bi][ji];
  }
  __syncthreads();

  if (t < 64) {
    float s = 0.f, q = 0.f;
    for (int b = 0; b < 64; ++b) { const float v = zb2[b * 64 + t]; s += v; q += v * v; }
    const float m = s * (1.0f / 64.0f);
    const float var = q * (1.0f / 64.0f) - m * m;
    const float sc = gm2[t] * rsqrtf(var + 1e-5f);
    sc2[t] = sc; sh2[t] = bem2[t] - m * sc;
  }
  __syncthreads();
  for (int idx = t; idx < 4096; idx += 256)
    zb2[idx] = fmaxf(zb2[idx] * sc2[idx & 63] + sh2[idx & 63], 0.0f);
  __syncthreads();

  if (t < 128) {
    const int b = t >> 1, c = t & 1;
    float s = bm3[c];
    for (int k = 0; k < 64; ++k) s += zb2[b * 64 + k] * Wm3[k * 2 + c];
    out[t] = s;
  }
}

// ---------------------------------------------------------------------------
extern "C" void kernel_launch(void* const* d_in, const int* in_sizes, int n_in,
                              void* d_out, int out_size, void* d_ws, size_t ws_size,
                              hipStream_t stream) {
  (void)in_sizes; (void)n_in; (void)out_size; (void)ws_size;
  const float* x    = (const float*)d_in[0];
  const float* mask = (const float*)d_in[1];
  const float* W1   = (const float*)d_in[2];
  const float* b1   = (const float*)d_in[3];
  const float* g1   = (const float*)d_in[4];
  const float* be1  = (const float*)d_in[5];
  const float* W2   = (const float*)d_in[6];
  const float* b2   = (const float*)d_in[7];
  const float* g2   = (const float*)d_in[8];
  const float* be2  = (const float*)d_in[9];
  const float* Wm1  = (const float*)d_in[10];
  // d_in[11] = bm1 (zeros; cancels under BN)
  const float* gm1  = (const float*)d_in[12];
  const float* bem1 = (const float*)d_in[13];
  const float* Wm2  = (const float*)d_in[14];
  // d_in[15] = bm2 (zeros; cancels under BN)
  const float* gm2  = (const float*)d_in[16];
  const float* bem2 = (const float*)d_in[17];
  const float* Wm3  = (const float*)d_in[18];
  const float* bm3  = (const float*)d_in[19];

  // workspace (floats), same extent as verified previously (117.67 MB)
  float* ws   = (float*)d_ws;
  float* T1   = ws;                 // 8,388,608 : bn-stat partials
  float* An   = T1 + 8388608;       // 4,194,304 : An -> head part2
  float* T2   = An + 4194304;       // 8,388,608 : XW1 -> XW2 -> head partials
  float* T3   = T2 + 8388608;       // 8,388,608 : pre1 -> pre2

  // fused independent stages: sim->An (blocks 0..255) + gemm1->T2 (256..767)
  k_simgemm<<<768, 256, 0, stream>>>(x, mask, An, W1, b1, T2);

  // layer 1 rest: pre1 = An @ XW1 (T3); stats -> T1
  k_bmmst<<<dim3(256, 2), 256, 0, stream>>>(An, T2, T3, T1);

  // layer 2: XW2 = relu(bn(pre1))@W2+b2 (stats replicated in-kernel), then
  // pre2 = An @ XW2; stats -> T1
  k_gemmbn_t<<<dim3(256, 2), 256, 0, stream>>>(T3, T1, g1, be1, W2, b2, T2);
  k_bmmst<<<dim3(256, 2), 256, 0, stream>>>(An, T2, T3, T1);

  // head: z1 = relu(bn(pre2)) @ Wm1 (stats replicated), split-K + reduce + tail
  k_headgemm_v3<<<1024, 256, 0, stream>>>(T3, T1, g2, be2, Wm1, T2);
  k_headredA<<<dim3(32, 8), 256, 0, stream>>>(T2, An);
  k_headtail<<<1, 256, 0, stream>>>(An, gm1, bem1, Wm2, gm2, bem2,
                                    Wm3, bm3, (float*)d_out);
}

// Round 17
// 398.198 us; speedup vs baseline: 1.1552x; 1.0402x over previous
//
#include <hip/hip_runtime.h>
#include <cstdint>
#include <cstddef>

// Shapes (fixed): B=64, N=4, P=128, d=h=256, totP=512, feat=131072
#define P_    128
#define H_    256
#define FEAT_ 131072

// ---------------------------------------------------------------------------
// FUSED independent-stage kernel: blocks 0..255 run the sim+deg+normalize
// body (-> An); blocks 256..767 run layer-1 gemm (x@W1+b1 -> XW1). Both
// depend only on x, so they are data-independent; fusing them co-schedules
// heterogeneous blocks per CU (independent stall patterns interleave).
// (R14-verified form, 405.7 us e2e.)
// ---------------------------------------------------------------------------
#define SIM_XS   0      // [16][128] = 2048
#define SIM_RED  2048   // [128][17] = 2176
#define SIM_DIAG 4224   // 128
#define SIM_INV  4352   // 128
#define SIM_DINV 4480   // 128  (total 4608)
#define GE_AS    0      // [16][132] = 2112
#define GE_WS    2112   // [16][132] = 2112 (total 4224)

__global__ __launch_bounds__(256) void k_simgemm(
    const float* __restrict__ x, const float* __restrict__ mask,
    float* __restrict__ An,
    const float* __restrict__ W, const float* __restrict__ bias,
    float* __restrict__ out) {
  __shared__ float smem[4608];
  const int bid = blockIdx.x;
  const int t = threadIdx.x, tp = t >> 4, tq = t & 15;

  if (bid < 256) {
    // ------------------- sim + deg + sym-normalize (R11 body) -------------
    const int blk = bid;
    const float* Xb = x + (size_t)blk * (128 * 256);

    float v[8][8];
    #pragma unroll
    for (int i = 0; i < 8; ++i)
      #pragma unroll
      for (int j = 0; j < 8; ++j) v[i][j] = 0.f;

    for (int kc = 0; kc < 16; ++kc) {
      __syncthreads();
      #pragma unroll
      for (int l = 0; l < 2; ++l) {
        const int f = t + 256 * l;
        const int row = f >> 2, k4 = (f & 3) * 4;
        const float4 x4 = *(const float4*)(Xb + (size_t)row * 256 + kc * 16 + k4);
        smem[SIM_XS + (k4 + 0) * 128 + row] = x4.x;
        smem[SIM_XS + (k4 + 1) * 128 + row] = x4.y;
        smem[SIM_XS + (k4 + 2) * 128 + row] = x4.z;
        smem[SIM_XS + (k4 + 3) * 128 + row] = x4.w;
      }
      __syncthreads();
      #pragma unroll
      for (int k = 0; k < 16; ++k) {
        const float4 a0 = *(const float4*)&smem[SIM_XS + k * 128 + tp * 8];
        const float4 a1 = *(const float4*)&smem[SIM_XS + k * 128 + tp * 8 + 4];
        const float4 b0 = *(const float4*)&smem[SIM_XS + k * 128 + tq * 8];
        const float4 b1 = *(const float4*)&smem[SIM_XS + k * 128 + tq * 8 + 4];
        const float a[8] = {a0.x, a0.y, a0.z, a0.w, a1.x, a1.y, a1.z, a1.w};
        const float b[8] = {b0.x, b0.y, b0.z, b0.w, b1.x, b1.y, b1.z, b1.w};
        #pragma unroll
        for (int i = 0; i < 8; ++i)
          #pragma unroll
          for (int j = 0; j < 8; ++j) v[i][j] += a[i] * b[j];
      }
    }

    // diagonal -> row norms -> inverse norms
    if (tp == tq) {
      #pragma unroll
      for (int i = 0; i < 8; ++i) smem[SIM_DIAG + tp * 8 + i] = v[i][i];
    }
    __syncthreads();
    if (t < 128)
      smem[SIM_INV + t] = 1.0f / fmaxf(sqrtf(smem[SIM_DIAG + t]), 1e-12f);
    __syncthreads();

    float ivq[8];
    #pragma unroll
    for (int j = 0; j < 8; ++j) ivq[j] = smem[SIM_INV + tq * 8 + j];

    #pragma unroll
    for (int i = 0; i < 8; ++i) {
      const int r = tp * 8 + i;
      const float ivp = smem[SIM_INV + r];
      const float4 m0 = *(const float4*)(mask + r * 128 + tq * 8);
      const float4 m1 = *(const float4*)(mask + r * 128 + tq * 8 + 4);
      const float mm[8] = {m0.x, m0.y, m0.z, m0.w, m1.x, m1.y, m1.z, m1.w};
      float s = 0.f;
      #pragma unroll
      for (int j = 0; j < 8; ++j) {
        const int c = tq * 8 + j;
        const float vv = (r == c) ? 0.0f
                                  : (v[i][j] * ivp * ivq[j] + 1.0f) * 0.5f * mm[j];
        v[i][j] = vv;
        s += vv;
      }
      smem[SIM_RED + r * 17 + tq] = s;
    }
    __syncthreads();
    if (t < 128) {
      float sm = 0.f;
      #pragma unroll
      for (int u = 0; u < 16; ++u) sm += smem[SIM_RED + t * 17 + u];
      const float deg = 1.0f + sm;
      smem[SIM_DINV + t] = (deg > 0.0f) ? rsqrtf(fmaxf(deg, 1e-12f)) : 0.0f;
    }
    __syncthreads();

    float dq[8];
    #pragma unroll
    for (int j = 0; j < 8; ++j) dq[j] = smem[SIM_DINV + tq * 8 + j];
    float* Ab = An + (size_t)blk * 16384;
    #pragma unroll
    for (int i = 0; i < 8; ++i) {
      const int r = tp * 8 + i;
      const float dp = smem[SIM_DINV + r];
      float o[8];
      #pragma unroll
      for (int j = 0; j < 8; ++j) {
        const int c = tq * 8 + j;
        o[j] = (r == c) ? dp * dq[j] : v[i][j] * dp * dq[j];
      }
      *(float4*)(Ab + (size_t)r * 128 + tq * 8)     = make_float4(o[0], o[1], o[2], o[3]);
      *(float4*)(Ab + (size_t)r * 128 + tq * 8 + 4) = make_float4(o[4], o[5], o[6], o[7]);
    }
  } else {
    // ------------------- layer-1 gemm: out = x@W + bias (R11 body) --------
    const int g = bid - 256;
    const int rb = g >> 1, cb = g & 1;
    const int m0 = rb * 128, c0 = cb * 128;

    float acc[8][8];
    #pragma unroll
    for (int j = 0; j < 8; ++j) {
      const int cj = (j < 4) ? (tq * 4 + j) : (64 + tq * 4 + (j - 4));
      const float bj = bias[c0 + cj];
      #pragma unroll
      for (int i = 0; i < 8; ++i) acc[i][j] = bj;
    }

    for (int kc = 0; kc < 16; ++kc) {
      __syncthreads();
      #pragma unroll
      for (int l = 0; l < 2; ++l) {   // stage A tile: 128 rows x 16 k
        const int f = t + 256 * l;
        const int row = f >> 2, k4 = (f & 3) * 4;
        const float4 a4 = *(const float4*)(x + (size_t)(m0 + row) * 256 + kc * 16 + k4);
        smem[GE_AS + (k4 + 0) * 132 + row] = a4.x;
        smem[GE_AS + (k4 + 1) * 132 + row] = a4.y;
        smem[GE_AS + (k4 + 2) * 132 + row] = a4.z;
        smem[GE_AS + (k4 + 3) * 132 + row] = a4.w;
      }
      #pragma unroll
      for (int l = 0; l < 2; ++l) {   // stage W tile: 16 k x 128 cols
        const int f = t + 256 * l;
        const int k = f >> 5, c4 = (f & 31) * 4;
        *(float4*)&smem[GE_WS + k * 132 + c4] =
            *(const float4*)(W + (size_t)(kc * 16 + k) * 256 + c0 + c4);
      }
      __syncthreads();
      #pragma unroll
      for (int k = 0; k < 16; ++k) {
        const float4 a0 = *(const float4*)&smem[GE_AS + k * 132 + tp * 4];
        const float4 a1 = *(const float4*)&smem[GE_AS + k * 132 + 64 + tp * 4];
        const float4 w0 = *(const float4*)&smem[GE_WS + k * 132 + tq * 4];
        const float4 w1 = *(const float4*)&smem[GE_WS + k * 132 + 64 + tq * 4];
        const float a[8] = {a0.x, a0.y, a0.z, a0.w, a1.x, a1.y, a1.z, a1.w};
        const float w[8] = {w0.x, w0.y, w0.z, w0.w, w1.x, w1.y, w1.z, w1.w};
        #pragma unroll
        for (int i = 0; i < 8; ++i)
          #pragma unroll
          for (int j = 0; j < 8; ++j) acc[i][j] += a[i] * w[j];
      }
    }

    #pragma unroll
    for (int i = 0; i < 8; ++i) {
      const int ri = (i < 4) ? (tp * 4 + i) : (64 + tp * 4 + (i - 4));
      float* orow = out + (size_t)(m0 + ri) * 256 + c0;
      *(float4*)(orow + tq * 4)      = make_float4(acc[i][0], acc[i][1], acc[i][2], acc[i][3]);
      *(float4*)(orow + 64 + tq * 4) = make_float4(acc[i][4], acc[i][5], acc[i][6], acc[i][7]);
    }
  }
}

// ---------------------------------------------------------------------------
// Tiled GEMM (layer 2), 128x128 8x8, fused BN+ReLU on A staging. (R11 form.)
// ---------------------------------------------------------------------------
__global__ __launch_bounds__(256) void k_gemmbn_t(
    const float* __restrict__ A, const float* __restrict__ scsh,
    const float* __restrict__ W, const float* __restrict__ bias,
    float* __restrict__ out) {
  __shared__ float As[16][132];
  __shared__ float Ws[16][132];
  const int rb = blockIdx.x, cb = blockIdx.y;
  const int t = threadIdx.x, tp = t >> 4, tq = t & 15;
  const int m0 = rb * 128, c0 = cb * 128;

  float acc[8][8];
  #pragma unroll
  for (int j = 0; j < 8; ++j) {
    const int cj = (j < 4) ? (tq * 4 + j) : (64 + tq * 4 + (j - 4));
    const float bj = bias[c0 + cj];
    #pragma unroll
    for (int i = 0; i < 8; ++i) acc[i][j] = bj;
  }

  for (int kc = 0; kc < 16; ++kc) {
    __syncthreads();
    #pragma unroll
    for (int l = 0; l < 2; ++l) {   // stage A tile with BN+ReLU (chan = k)
      const int f = t + 256 * l;
      const int row = f >> 2, k4 = (f & 3) * 4;
      const int col = kc * 16 + k4;
      const float4 a4 = *(const float4*)(A + (size_t)(m0 + row) * 256 + col);
      const float4 sc = *(const float4*)(scsh + col);
      const float4 sh = *(const float4*)(scsh + 256 + col);
      As[k4 + 0][row] = fmaxf(a4.x * sc.x + sh.x, 0.0f);
      As[k4 + 1][row] = fmaxf(a4.y * sc.y + sh.y, 0.0f);
      As[k4 + 2][row] = fmaxf(a4.z * sc.z + sh.z, 0.0f);
      As[k4 + 3][row] = fmaxf(a4.w * sc.w + sh.w, 0.0f);
    }
    #pragma unroll
    for (int l = 0; l < 2; ++l) {
      const int f = t + 256 * l;
      const int k = f >> 5, c4 = (f & 31) * 4;
      *(float4*)&Ws[k][c4] =
          *(const float4*)(W + (size_t)(kc * 16 + k) * 256 + c0 + c4);
    }
    __syncthreads();
    #pragma unroll
    for (int k = 0; k < 16; ++k) {
      const float4 a0 = *(const float4*)&As[k][tp * 4];
      const float4 a1 = *(const float4*)&As[k][64 + tp * 4];
      const float4 w0 = *(const float4*)&Ws[k][tq * 4];
      const float4 w1 = *(const float4*)&Ws[k][64 + tq * 4];
      const float a[8] = {a0.x, a0.y, a0.z, a0.w, a1.x, a1.y, a1.z, a1.w};
      const float w[8] = {w0.x, w0.y, w0.z, w0.w, w1.x, w1.y, w1.z, w1.w};
      #pragma unroll
      for (int i = 0; i < 8; ++i)
        #pragma unroll
        for (int j = 0; j < 8; ++j) acc[i][j] += a[i] * w[j];
    }
  }

  #pragma unroll
  for (int i = 0; i < 8; ++i) {
    const int ri = (i < 4) ? (tp * 4 + i) : (64 + tp * 4 + (i - 4));
    float* orow = out + (size_t)(m0 + ri) * 256 + c0;
    *(float4*)(orow + tq * 4)      = make_float4(acc[i][0], acc[i][1], acc[i][2], acc[i][3]);
    *(float4*)(orow + 64 + tq * 4) = make_float4(acc[i][4], acc[i][5], acc[i][6], acc[i][7]);
  }
}

// ---------------------------------------------------------------------------
// Tiled bmm + fused BN-stat partials. 128x128 tile, 8x8/thread, grid (256,2).
// Stats -> part[(blk*2+cb)*256 + {c | 128+c}]. (R11 form.)
// ---------------------------------------------------------------------------
__global__ __launch_bounds__(256) void k_bmmst(
    const float* __restrict__ An, const float* __restrict__ XW,
    float* __restrict__ out, float* __restrict__ part) {
  __shared__ float As[16][132];   // [q][p]
  __shared__ float Ws[16][132];   // [q][c]
  __shared__ float rs[16][128];
  __shared__ float rq[16][128];
  const int blk = blockIdx.x, cb = blockIdx.y;
  const int t = threadIdx.x, tp = t >> 4, tq = t & 15;
  const float* Ab = An + (size_t)blk * 16384;        // [128][128]
  const float* Xb = XW + (size_t)blk * (128 * 256);  // [128][256]

  float acc[8][8];
  #pragma unroll
  for (int i = 0; i < 8; ++i)
    #pragma unroll
    for (int j = 0; j < 8; ++j) acc[i][j] = 0.f;

  for (int kc = 0; kc < 8; ++kc) {     // K=128, ascending q
    __syncthreads();
    #pragma unroll
    for (int l = 0; l < 2; ++l) {      // stage An tile: 128 p x 16 q
      const int f = t + 256 * l;
      const int row = f >> 2, k4 = (f & 3) * 4;
      const float4 a4 = *(const float4*)(Ab + (size_t)row * 128 + kc * 16 + k4);
      As[k4 + 0][row] = a4.x;
      As[k4 + 1][row] = a4.y;
      As[k4 + 2][row] = a4.z;
      As[k4 + 3][row] = a4.w;
    }
    #pragma unroll
    for (int l = 0; l < 2; ++l) {      // stage XW tile: 16 q x 128 c
      const int f = t + 256 * l;
      const int k = f >> 5, c4 = (f & 31) * 4;
      *(float4*)&Ws[k][c4] =
          *(const float4*)(Xb + (size_t)(kc * 16 + k) * 256 + cb * 128 + c4);
    }
    __syncthreads();
    #pragma unroll
    for (int k = 0; k < 16; ++k) {
      const float4 a0 = *(const float4*)&As[k][tp * 4];
      const float4 a1 = *(const float4*)&As[k][64 + tp * 4];
      const float4 w0 = *(const float4*)&Ws[k][tq * 4];
      const float4 w1 = *(const float4*)&Ws[k][64 + tq * 4];
      const float a[8] = {a0.x, a0.y, a0.z, a0.w, a1.x, a1.y, a1.z, a1.w};
      const float w[8] = {w0.x, w0.y, w0.z, w0.w, w1.x, w1.y, w1.z, w1.w};
      #pragma unroll
      for (int i = 0; i < 8; ++i)
        #pragma unroll
        for (int j = 0; j < 8; ++j) acc[i][j] += a[i] * w[j];
    }
  }

  // stats: per-thread col partial over 8 rows -> LDS -> 128-thread final
  #pragma unroll
  for (int j = 0; j < 8; ++j) {
    const int col = (j < 4) ? (tq * 4 + j) : (64 + tq * 4 + (j - 4));
    float cs = 0.f, cq = 0.f;
    #pragma unroll
    for (int i = 0; i < 8; ++i) { cs += acc[i][j]; cq += acc[i][j] * acc[i][j]; }
    rs[tp][col] = cs;
    rq[tp][col] = cq;
  }
  __syncthreads();
  if (t < 128) {
    float s = 0.f, q = 0.f;
    #pragma unroll
    for (int u = 0; u < 16; ++u) { s += rs[u][t]; q += rq[u][t]; }
    const int base = (blk * 2 + cb) * 256;
    part[base + t]       = s;
    part[base + 128 + t] = q;
  }

  #pragma unroll
  for (int i = 0; i < 8; ++i) {
    const int ri = (i < 4) ? (tp * 4 + i) : (64 + tp * 4 + (i - 4));
    float* orow = out + (size_t)(blk * 128 + ri) * 256 + cb * 128;
    *(float4*)(orow + tq * 4)      = make_float4(acc[i][0], acc[i][1], acc[i][2], acc[i][3]);
    *(float4*)(orow + 64 + tq * 4) = make_float4(acc[i][4], acc[i][5], acc[i][6], acc[i][7]);
  }
}

// ---------------------------------------------------------------------------
// bn final + scsh: block per channel (256 blocks x 256 thr). Deterministic.
// ---------------------------------------------------------------------------
__global__ __launch_bounds__(256) void k_bnscsh(
    const float* __restrict__ part, const float* __restrict__ g,
    const float* __restrict__ be, float* __restrict__ scsh) {
  __shared__ float ss[256], qq[256];
  const int c = blockIdx.x;
  const int cb = c >> 7, lc = c & 127;
  const int u = threadIdx.x;           // = blk
  const float* pb = part + (size_t)(u * 2 + cb) * 256;
  ss[u] = pb[lc];
  qq[u] = pb[128 + lc];
  __syncthreads();
  for (int st = 128; st; st >>= 1) {
    if (u < st) { ss[u] += ss[u + st]; qq[u] += qq[u + st]; }
    __syncthreads();
  }
  if (u == 0) {
    const float m = ss[0] * (1.0f / 32768.0f);
    const float var = qq[0] * (1.0f / 32768.0f) - m * m;
    const float sc = g[c] * rsqrtf(var + 1e-5f);
    scsh[c] = sc;
    scsh[256 + c] = be[c] - m * sc;
  }
}

// ---------------------------------------------------------------------------
// head split-K GEMM v3: 1024 blocks (K-chunk 128) x 256 thr. Graph chunk
// staged in LDS with BN+ReLU applied once. Partials -> part (1024 x 8192).
// ---------------------------------------------------------------------------
__global__ __launch_bounds__(256) void k_headgemm_v3(
    const float* __restrict__ pre2, const float* __restrict__ scsh,
    const float* __restrict__ Wm1, float* __restrict__ part) {
  __shared__ float graphS[64][128];   // 32 KB
  const int t = threadIdx.x;
  const int bid = blockIdx.x;
  const int k0 = bid * 128;
  const int cbase = k0 & 255;

  #pragma unroll
  for (int l = 0; l < 8; ++l) {
    const int f = t + 256 * l;
    const int row = f >> 5, c4 = (f & 31) * 4;
    const float4 p = *(const float4*)(pre2 + (size_t)row * FEAT_ + k0 + c4);
    const float4 sc = *(const float4*)(scsh + cbase + c4);
    const float4 sh = *(const float4*)(scsh + 256 + cbase + c4);
    graphS[row][c4 + 0] = fmaxf(p.x * sc.x + sh.x, 0.0f);
    graphS[row][c4 + 1] = fmaxf(p.y * sc.y + sh.y, 0.0f);
    graphS[row][c4 + 2] = fmaxf(p.z * sc.z + sh.z, 0.0f);
    graphS[row][c4 + 3] = fmaxf(p.w * sc.w + sh.w, 0.0f);
  }
  __syncthreads();

  const int hg = t & 31;
  const int bg = t >> 5;
  float acc[8][4];
  #pragma unroll
  for (int i = 0; i < 8; ++i)
    #pragma unroll
    for (int j = 0; j < 4; ++j) acc[i][j] = 0.f;

  #pragma unroll 2
  for (int kk = 0; kk < 128; kk += 4) {
    const int k = k0 + kk;
    const float4 w0 = *(const float4*)(Wm1 + (size_t)(k + 0) * 128 + hg * 4);
    const float4 w1 = *(const float4*)(Wm1 + (size_t)(k + 1) * 128 + hg * 4);
    const float4 w2 = *(const float4*)(Wm1 + (size_t)(k + 2) * 128 + hg * 4);
    const float4 w3 = *(const float4*)(Wm1 + (size_t)(k + 3) * 128 + hg * 4);
    #pragma unroll
    for (int i = 0; i < 8; ++i) {
      const float4 a = *(const float4*)&graphS[bg * 8 + i][kk];
      acc[i][0] += a.x * w0.x; acc[i][1] += a.x * w0.y;
      acc[i][2] += a.x * w0.z; acc[i][3] += a.x * w0.w;
      acc[i][0] += a.y * w1.x; acc[i][1] += a.y * w1.y;
      acc[i][2] += a.y * w1.z; acc[i][3] += a.y * w1.w;
      acc[i][0] += a.z * w2.x; acc[i][1] += a.z * w2.y;
      acc[i][2] += a.z * w2.z; acc[i][3] += a.z * w2.w;
      acc[i][0] += a.w * w3.x; acc[i][1] += a.w * w3.y;
      acc[i][2] += a.w * w3.z; acc[i][3] += a.w * w3.w;
    }
  }

  float* pb = part + (size_t)bid * 8192;
  #pragma unroll
  for (int i = 0; i < 8; ++i)
    *(float4*)(pb + (bg * 8 + i) * 128 + hg * 4) =
        make_float4(acc[i][0], acc[i][1], acc[i][2], acc[i][3]);
}

// ---------------------------------------------------------------------------
// head reduce stage A: part2[jg][o] = sum of 128 consecutive partials.
// ---------------------------------------------------------------------------
__global__ __launch_bounds__(256) void k_headredA(
    const float* __restrict__ part, float* __restrict__ part2) {
  const int o = blockIdx.x * 256 + threadIdx.x;
  const int jg = blockIdx.y;
  const float* base = part + (size_t)jg * 128 * 8192;
  float s = 0.f;
  for (int j = 0; j < 128; ++j) s += base[(size_t)j * 8192 + o];
  part2[(size_t)jg * 8192 + o] = s;
}

// ---------------------------------------------------------------------------
// Fused head tail: z1 reduce -> BN1+ReLU -> mm2 -> BN2+ReLU -> out.
// ONE block, 256 threads, everything in LDS. (R10/R14-verified form.)
// ---------------------------------------------------------------------------
__global__ __launch_bounds__(256) void k_headtail(
    const float* __restrict__ part2,
    const float* __restrict__ gm1, const float* __restrict__ bem1,
    const float* __restrict__ Wm2,
    const float* __restrict__ gm2, const float* __restrict__ bem2,
    const float* __restrict__ Wm3, const float* __restrict__ bm3,
    float* __restrict__ out) {
  __shared__ float zs[8192];     // z1 / zr1 (64x128)
  __shared__ float wm2s[8192];   // Wm2 (128x64)
  __shared__ float zb2[4096];    // z2 / zr2 (64x64)
  __shared__ float sc1[128], sh1[128], sc2[64], sh2[64];
  const int t = threadIdx.x;

  for (int o = t; o < 8192; o += 256) {
    float s = 0.f;
    #pragma unroll
    for (int jg = 0; jg < 8; ++jg) s += part2[(size_t)jg * 8192 + o];
    zs[o] = s;
  }
  for (int o = t; o < 8192; o += 256) wm2s[o] = Wm2[o];
  __syncthreads();

  if (t < 128) {
    float s = 0.f, q = 0.f;
    for (int b = 0; b < 64; ++b) { const float v = zs[b * 128 + t]; s += v; q += v * v; }
    const float m = s * (1.0f / 64.0f);
    const float var = q * (1.0f / 64.0f) - m * m;
    const float sc = gm1[t] * rsqrtf(var + 1e-5f);
    sc1[t] = sc; sh1[t] = bem1[t] - m * sc;
  }
  __syncthreads();
  for (int o = t; o < 8192; o += 256)
    zs[o] = fmaxf(zs[o] * sc1[o & 127] + sh1[o & 127], 0.0f);
  __syncthreads();

  {
    const int bq = t >> 4, jq = t & 15;
    float acc[4][4];
    #pragma unroll
    for (int bi = 0; bi < 4; ++bi)
      #pragma unroll
      for (int ji = 0; ji < 4; ++ji) acc[bi][ji] = 0.f;
    for (int k = 0; k < 128; ++k) {
      const float4 w4 = *(const float4*)&wm2s[k * 64 + jq * 4];
      const float wv[4] = {w4.x, w4.y, w4.z, w4.w};
      #pragma unroll
      for (int bi = 0; bi < 4; ++bi) {
        const float zv = zs[(bq * 4 + bi) * 128 + k];
        #pragma unroll
        for (int ji = 0; ji < 4; ++ji) acc[bi][ji] += zv * wv[ji];
      }
    }
    #pragma unroll
    for (int bi = 0; bi < 4; ++bi)
      #pragma unroll
      for (int ji = 0; ji < 4; ++ji)
        zb2[(bq * 4 + bi) * 64 + jq * 4 + ji] = acc[bi][ji];
  }
  __syncthreads();

  if (t < 64) {
    float s = 0.f, q = 0.f;
    for (int b = 0; b < 64; ++b) { const float v = zb2[b * 64 + t]; s += v; q += v * v; }
    const float m = s * (1.0f / 64.0f);
    const float var = q * (1.0f / 64.0f) - m * m;
    const float sc = gm2[t] * rsqrtf(var + 1e-5f);
    sc2[t] = sc; sh2[t] = bem2[t] - m * sc;
  }
  __syncthreads();
  for (int idx = t; idx < 4096; idx += 256)
    zb2[idx] = fmaxf(zb2[idx] * sc2[idx & 63] + sh2[idx & 63], 0.0f);
  __syncthreads();

  if (t < 128) {
    const int b = t >> 1, c = t & 1;
    float s = bm3[c];
    for (int k = 0; k < 64; ++k) s += zb2[b * 64 + k] * Wm3[k * 2 + c];
    out[t] = s;
  }
}

// ---------------------------------------------------------------------------
extern "C" void kernel_launch(void* const* d_in, const int* in_sizes, int n_in,
                              void* d_out, int out_size, void* d_ws, size_t ws_size,
                              hipStream_t stream) {
  (void)in_sizes; (void)n_in; (void)out_size; (void)ws_size;
  const float* x    = (const float*)d_in[0];
  const float* mask = (const float*)d_in[1];
  const float* W1   = (const float*)d_in[2];
  const float* b1   = (const float*)d_in[3];
  const float* g1   = (const float*)d_in[4];
  const float* be1  = (const float*)d_in[5];
  const float* W2   = (const float*)d_in[6];
  const float* b2   = (const float*)d_in[7];
  const float* g2   = (const float*)d_in[8];
  const float* be2  = (const float*)d_in[9];
  const float* Wm1  = (const float*)d_in[10];
  // d_in[11] = bm1 (zeros; cancels under BN)
  const float* gm1  = (const float*)d_in[12];
  const float* bem1 = (const float*)d_in[13];
  const float* Wm2  = (const float*)d_in[14];
  // d_in[15] = bm2 (zeros; cancels under BN)
  const float* gm2  = (const float*)d_in[16];
  const float* bem2 = (const float*)d_in[17];
  const float* Wm3  = (const float*)d_in[18];
  const float* bm3  = (const float*)d_in[19];

  // workspace (floats), same extent as verified previously (117.67 MB)
  float* ws   = (float*)d_ws;
  float* T1   = ws;                 // 8,388,608 : bn-stat partials
  float* An   = T1 + 8388608;       // 4,194,304 : An -> head part2
  float* T2   = An + 4194304;       // 8,388,608 : XW1 -> XW2 -> head partials
  float* T3   = T2 + 8388608;       // 8,388,608 : pre1 -> pre2
  float* z1   = T3 + 8388608;       // 8,192 (unused)
  float* dinv = z1 + 8192;          // 32,768 : scsh1 at +0, scsh2 at +512
  (void)z1;

  float* scsh1 = dinv;
  float* scsh2 = dinv + 512;

  // fused independent stages: sim->An (blocks 0..255) + gemm1->T2 (256..767)
  k_simgemm<<<768, 256, 0, stream>>>(x, mask, An, W1, b1, T2);

  // layer 1 rest: pre1 = An @ XW1 (T3); stats -> T1
  k_bmmst<<<dim3(256, 2), 256, 0, stream>>>(An, T2, T3, T1);
  k_bnscsh<<<256, 256, 0, stream>>>(T1, g1, be1, scsh1);

  // layer 2: pre2 = An @ (relu(bn(pre1))@W2+b2); bn fused into A-staging
  k_gemmbn_t<<<dim3(256, 2), 256, 0, stream>>>(T3, scsh1, W2, b2, T2);
  k_bmmst<<<dim3(256, 2), 256, 0, stream>>>(An, T2, T3, T1);
  k_bnscsh<<<256, 256, 0, stream>>>(T1, g2, be2, scsh2);

  // head: z1 = relu(bn(pre2)) @ Wm1, split-K + reduce + fused tail
  k_headgemm_v3<<<1024, 256, 0, stream>>>(T3, scsh2, Wm1, T2);
  k_headredA<<<dim3(32, 8), 256, 0, stream>>>(T2, An);
  k_headtail<<<1, 256, 0, stream>>>(An, gm1, bem1, Wm2, gm2, bem2,
                                    Wm3, bm3, (float*)d_out);
}